// Round 1
// baseline (139.158 us; speedup 1.0000x reference)
//
#include <hip/hip_runtime.h>

#define EPSF 1e-8f
#define DD 128   // feature dim, fixed by problem

// ---------- small helpers ----------
__device__ __forceinline__ float4 ld4(const float* p){ return *reinterpret_cast<const float4*>(p); }
__device__ __forceinline__ void st4(float* p, const float4& v){ *reinterpret_cast<float4*>(p) = v; }
__device__ __forceinline__ float dot4(const float4& a, const float4& b){
  return a.x*b.x + a.y*b.y + a.z*b.z + a.w*b.w;
}
__device__ __forceinline__ void fma4(float4& acc, const float4& a, float s){
  acc.x += a.x*s; acc.y += a.y*s; acc.z += a.z*s; acc.w += a.w*s;
}
// (1-a)*v + a*x  (matches reference arithmetic order)
__device__ __forceinline__ float4 mix4(float a, const float4& v, const float4& x){
  float4 r;
  r.x = (1.f-a)*v.x + a*x.x;
  r.y = (1.f-a)*v.y + a*x.y;
  r.z = (1.f-a)*v.z + a*x.z;
  r.w = (1.f-a)*v.w + a*x.w;
  return r;
}
// butterfly sum over a 32-lane group (masks <32 stay within each wave half)
__device__ __forceinline__ float red32(float v){
  v += __shfl_xor(v, 1);
  v += __shfl_xor(v, 2);
  v += __shfl_xor(v, 4);
  v += __shfl_xor(v, 8);
  v += __shfl_xor(v, 16);
  return v;
}
// block-level reduction of 8 row-groups' float4 partials into dst[0..127]
__device__ __forceinline__ void block_red(float* red, int group, int l, int t,
                                          const float4& acc, float* dst){
  red[group*DD + l*4+0] = acc.x;
  red[group*DD + l*4+1] = acc.y;
  red[group*DD + l*4+2] = acc.z;
  red[group*DD + l*4+3] = acc.w;
  __syncthreads();
  if (t < DD){
    float s = 0.f;
    #pragma unroll
    for (int g = 0; g < 8; ++g) s += red[g*DD + t];
    dst[t] = s;
  }
  __syncthreads();
}

// ---------- kernel A: cs0 = cos(at_addr, addresses); partials for fn_addr, arg_addr ----------
__global__ __launch_bounds__(256) void kA(const float* __restrict__ at,
                                          const float* __restrict__ addr,
                                          const float* __restrict__ col1,
                                          const float* __restrict__ col2,
                                          float* __restrict__ cs0,
                                          float* __restrict__ part,
                                          int B, int N, int chunks){
  __shared__ float red[8*DD];
  int blk = blockIdx.x;
  int b = blk / chunks, c = blk % chunks;
  int rows = N / chunks, n0 = c * rows;
  int t = threadIdx.x, lane = t & 63, wave = t >> 6, l = lane & 31;
  int group = wave*2 + (lane >> 5);           // 0..7, each group = 32 lanes = 1 row

  float4 at4 = ld4(at + (size_t)b*DD + l*4);
  float nat = sqrtf(red32(dot4(at4, at4)));

  float4 accF = make_float4(0,0,0,0), accA = make_float4(0,0,0,0);
  for (int r = group; r < rows; r += 8){
    size_t n = (size_t)n0 + r;
    size_t off = ((size_t)b*N + n)*DD + l*4;
    float4 a4 = ld4(addr + off);
    float dp = red32(dot4(at4, a4));
    float n2 = red32(dot4(a4, a4));
    float cs = dp / fmaxf(nat * sqrtf(n2), EPSF);
    if (l == 0) cs0[(size_t)b*N + n] = cs;
    float4 c1 = ld4(col1 + off), c2 = ld4(col2 + off);
    fma4(accF, c1, cs);
    fma4(accA, c2, cs);
  }
  block_red(red, group, l, t, accF, part + (((size_t)(0*B + b))*chunks + c)*DD);
  block_red(red, group, l, t, accA, part + (((size_t)(1*B + b))*chunks + c)*DD);
}

// ---------- finalize: dst[vec][b][d] = sum_c part[vec][b][c][d] ----------
__global__ void kFin(const float* __restrict__ part, float* __restrict__ dst,
                     int nvec, int B, int chunks){
  int i = blockIdx.x*blockDim.x + threadIdx.x;
  int total = nvec * B * DD;
  if (i >= total) return;
  int d = i & (DD-1);
  int vb = i >> 7;                 // vec*B + b
  const float* p = part + ((size_t)vb*chunks)*DD + d;
  float s = 0.f;
  for (int c = 0; c < chunks; ++c) s += p[(size_t)c*DD];
  dst[i] = s;
}

// ---------- kernel B: cs_fn, cs_arg; partials for param,body,a_tag,a_l,a_r ----------
__global__ __launch_bounds__(256) void kB(const float* __restrict__ addr,
                                          const float* __restrict__ tags,
                                          const float* __restrict__ col1,
                                          const float* __restrict__ col2,
                                          const float* __restrict__ vecs,
                                          float* __restrict__ csfn,
                                          float* __restrict__ part,
                                          int B, int N, int chunks){
  __shared__ float red[8*DD];
  int blk = blockIdx.x;
  int b = blk / chunks, c = blk % chunks;
  int rows = N / chunks, n0 = c * rows;
  int t = threadIdx.x, lane = t & 63, wave = t >> 6, l = lane & 31;
  int group = wave*2 + (lane >> 5);

  float4 fn4 = ld4(vecs + ((size_t)0*B + b)*DD + l*4);
  float4 ag4 = ld4(vecs + ((size_t)1*B + b)*DD + l*4);
  float nfn = sqrtf(red32(dot4(fn4, fn4)));
  float nag = sqrtf(red32(dot4(ag4, ag4)));

  float4 accP = make_float4(0,0,0,0), accB = accP, accT = accP, accL = accP, accR = accP;
  for (int r = group; r < rows; r += 8){
    size_t n = (size_t)n0 + r;
    size_t off = ((size_t)b*N + n)*DD + l*4;
    float4 a4 = ld4(addr + off);
    float dfn = red32(dot4(fn4, a4));
    float dag = red32(dot4(ag4, a4));
    float n2  = red32(dot4(a4, a4));
    float na = sqrtf(n2);
    float cf = dfn / fmaxf(nfn*na, EPSF);
    float ca = dag / fmaxf(nag*na, EPSF);
    if (l == 0) csfn[(size_t)b*N + n] = cf;
    float4 t4 = ld4(tags + off), c1 = ld4(col1 + off), c2 = ld4(col2 + off);
    fma4(accP, c1, cf);      // param_addr
    fma4(accB, c2, cf);      // body_addr
    fma4(accT, t4, ca);      // a_tag
    fma4(accL, c1, ca);      // a_l
    fma4(accR, c2, ca);      // a_r
  }
  block_red(red, group, l, t, accP, part + (((size_t)(0*B + b))*chunks + c)*DD);
  block_red(red, group, l, t, accB, part + (((size_t)(1*B + b))*chunks + c)*DD);
  block_red(red, group, l, t, accT, part + (((size_t)(2*B + b))*chunks + c)*DD);
  block_red(red, group, l, t, accL, part + (((size_t)(3*B + b))*chunks + c)*DD);
  block_red(red, group, l, t, accR, part + (((size_t)(4*B + b))*chunks + c)*DD);
}

// ---------- kernel C: param-insert + replaces (row-local), write updated tensors,
//            reduce b_tag/b_l/b_r weighted by cs_body ----------
__global__ __launch_bounds__(256) void kC(const float* __restrict__ addr,
                                          const float* __restrict__ tags,
                                          const float* __restrict__ col1,
                                          const float* __restrict__ col2,
                                          const float* __restrict__ vecs,
                                          float* __restrict__ alphap,
                                          float* __restrict__ csbody,
                                          float* __restrict__ o_t,
                                          float* __restrict__ o_1,
                                          float* __restrict__ o_2,
                                          float* __restrict__ part,
                                          int B, int N, int chunks){
  __shared__ float red[8*DD];
  int blk = blockIdx.x;
  int b = blk / chunks, c = blk % chunks;
  int rows = N / chunks, n0 = c * rows;
  int t = threadIdx.x, lane = t & 63, wave = t >> 6, l = lane & 31;
  int group = wave*2 + (lane >> 5);

  size_t BD = (size_t)B*DD;
  float4 ag4 = ld4(vecs + 1*BD + (size_t)b*DD + l*4);   // arg_addr
  float4 pm4 = ld4(vecs + 2*BD + (size_t)b*DD + l*4);   // param_addr
  float4 bd4 = ld4(vecs + 3*BD + (size_t)b*DD + l*4);   // body_addr
  float4 xt4 = ld4(vecs + 4*BD + (size_t)b*DD + l*4);   // a_tag
  float4 xl4 = ld4(vecs + 5*BD + (size_t)b*DD + l*4);   // a_l
  float4 xr4 = ld4(vecs + 6*BD + (size_t)b*DD + l*4);   // a_r
  float npm = sqrtf(red32(dot4(pm4, pm4)));
  float nbd = sqrtf(red32(dot4(bd4, bd4)));

  float4 accT = make_float4(0,0,0,0), accL = accT, accR = accT;
  for (int r = group; r < rows; r += 8){
    size_t n = (size_t)n0 + r;
    size_t off = ((size_t)b*N + n)*DD + l*4;
    float4 a4 = ld4(addr + off);
    float dp  = red32(dot4(pm4, a4));
    float db  = red32(dot4(bd4, a4));
    float n2a = red32(dot4(a4, a4));
    float na = sqrtf(n2a);
    float csp = dp / fmaxf(npm*na, EPSF);
    float ap  = csp > EPSF ? csp : 0.f;
    float csb = db / fmaxf(nbd*na, EPSF);
    if (l == 0){ alphap[(size_t)b*N + n] = ap; csbody[(size_t)b*N + n] = csb; }

    float4 t4 = ld4(tags + off), c1 = ld4(col1 + off), c2 = ld4(col2 + off);
    // kv_insert with param_addr
    float4 tn  = mix4(ap, t4, xt4);
    float4 c1n = mix4(ap, c1, xl4);
    float4 c2n = mix4(ap, c2, xr4);
    // replace(arg_addr, param_addr, col1'): sim vs updated row itself (no clamp)
    float d1  = red32(dot4(pm4, c1n));
    float n21 = red32(dot4(c1n, c1n));
    float s1 = d1 / fmaxf(npm * sqrtf(n21), EPSF);
    float4 c1f = mix4(s1, c1n, ag4);
    float d2  = red32(dot4(pm4, c2n));
    float n22 = red32(dot4(c2n, c2n));
    float s2 = d2 / fmaxf(npm * sqrtf(n22), EPSF);
    float4 c2f = mix4(s2, c2n, ag4);

    st4(o_t + off, tn);
    st4(o_1 + off, c1f);
    st4(o_2 + off, c2f);
    // select_address(body_addr, ...) over UPDATED tensors
    fma4(accT, tn,  csb);
    fma4(accL, c1f, csb);
    fma4(accR, c2f, csb);
  }
  block_red(red, group, l, t, accT, part + (((size_t)(0*B + b))*chunks + c)*DD);
  block_red(red, group, l, t, accL, part + (((size_t)(1*B + b))*chunks + c)*DD);
  block_red(red, group, l, t, accR, part + (((size_t)(2*B + b))*chunks + c)*DD);
}

// ---------- kernel D: at_addr insert + collapsed GC, in place on d_out ----------
__global__ __launch_bounds__(256) void kD(float* __restrict__ o_t,
                                          float* __restrict__ o_1,
                                          float* __restrict__ o_2,
                                          const float* __restrict__ cs0,
                                          const float* __restrict__ csfn,
                                          const float* __restrict__ alphap,
                                          const float* __restrict__ csbody,
                                          const float* __restrict__ vecs,
                                          const float* __restrict__ zv,
                                          const int* __restrict__ gcp,
                                          int B, int N){
  size_t i = (size_t)blockIdx.x*blockDim.x + threadIdx.x;
  size_t total = (size_t)B*N*(DD/4);
  if (i >= total) return;
  int l = (int)(i & 31);
  size_t bn = i >> 5;
  int b = (int)(bn / (size_t)N);

  float c0 = cs0[bn], cf = csfn[bn], ap = alphap[bn], cb = csbody[bn];
  float aat = c0 > EPSF ? c0 : 0.f;
  float af  = cf > EPSF ? cf : 0.f;
  float ab  = cb > EPSF ? cb : 0.f;
  float q = (1.f-af)*(1.f-ap)*(1.f-ab);
  int gc = gcp[0];
  float P = 1.f;
  for (int k = 0; k < gc; ++k) P *= q;

  size_t BD = (size_t)B*DD;
  const float* vb = vecs + 7*BD + (size_t)b*DD + l*4;
  float4 bt = ld4(vb), bl = ld4(vb + BD), br = ld4(vb + 2*BD);
  float4 z4 = ld4(zv + l*4);

  size_t off = bn*DD + (size_t)l*4;
  float4 v, u;
  v = ld4(o_t + off); u = mix4(aat, v, bt);
  u.x = P*u.x + (1.f-P)*z4.x; u.y = P*u.y + (1.f-P)*z4.y;
  u.z = P*u.z + (1.f-P)*z4.z; u.w = P*u.w + (1.f-P)*z4.w;
  st4(o_t + off, u);
  v = ld4(o_1 + off); u = mix4(aat, v, bl);
  u.x = P*u.x + (1.f-P)*z4.x; u.y = P*u.y + (1.f-P)*z4.y;
  u.z = P*u.z + (1.f-P)*z4.z; u.w = P*u.w + (1.f-P)*z4.w;
  st4(o_1 + off, u);
  v = ld4(o_2 + off); u = mix4(aat, v, br);
  u.x = P*u.x + (1.f-P)*z4.x; u.y = P*u.y + (1.f-P)*z4.y;
  u.z = P*u.z + (1.f-P)*z4.z; u.w = P*u.w + (1.f-P)*z4.w;
  st4(o_2 + off, u);
}

extern "C" void kernel_launch(void* const* d_in, const int* in_sizes, int n_in,
                              void* d_out, int out_size, void* d_ws, size_t ws_size,
                              hipStream_t stream){
  const float* at   = (const float*)d_in[0];
  const float* addr = (const float*)d_in[1];
  const float* tags = (const float*)d_in[2];
  const float* col1 = (const float*)d_in[3];
  const float* col2 = (const float*)d_in[4];
  const float* zv   = (const float*)d_in[5];
  const int*   gc   = (const int*)d_in[6];

  int Dd = in_sizes[5];                 // 128
  int B  = in_sizes[0] / Dd;            // 32
  int N  = in_sizes[1] / in_sizes[0];   // 2048
  (void)Dd;

  // workspace layout (floats)
  float* w = (float*)d_ws;
  size_t S  = (size_t)B * N;
  size_t BD = (size_t)B * DD;
  float* cs0    = w;
  float* csfn   = w + S;
  float* alphap = w + 2*S;
  float* csbody = w + 3*S;
  float* vecs   = w + 4*S;              // [10][B][D]: fn,arg,param,body,a_tag,a_l,a_r,b_tag,b_l,b_r
  float* part   = vecs + 10*BD;         // up to [5][B][CH][D]

  float* o_t = (float*)d_out;
  float* o_1 = o_t + (size_t)B*N*DD;
  float* o_2 = o_1 + (size_t)B*N*DD;

  const int CH = 32;                    // n-chunks per batch
  dim3 blk(256);
  dim3 grid(B*CH);

  kA<<<grid, blk, 0, stream>>>(at, addr, col1, col2, cs0, part, B, N, CH);
  {
    int tot = 2*B*DD;
    kFin<<<(tot+255)/256, 256, 0, stream>>>(part, vecs + 0*BD, 2, B, CH);
  }
  kB<<<grid, blk, 0, stream>>>(addr, tags, col1, col2, vecs, csfn, part, B, N, CH);
  {
    int tot = 5*B*DD;
    kFin<<<(tot+255)/256, 256, 0, stream>>>(part, vecs + 2*BD, 5, B, CH);
  }
  kC<<<grid, blk, 0, stream>>>(addr, tags, col1, col2, vecs, alphap, csbody,
                               o_t, o_1, o_2, part, B, N, CH);
  {
    int tot = 3*B*DD;
    kFin<<<(tot+255)/256, 256, 0, stream>>>(part, vecs + 7*BD, 3, B, CH);
  }
  {
    size_t tot = (size_t)B*N*(DD/4);
    kD<<<(unsigned)((tot+255)/256), 256, 0, stream>>>(o_t, o_1, o_2, cs0, csfn, alphap,
                                                      csbody, vecs, zv, gc, B, N);
  }
}